// Round 1
// baseline (2627.967 us; speedup 1.0000x reference)
//
#include <hip/hip_runtime.h>
#include <math.h>

// Problem: B=1024, S=512, D=200, A=100
//   uit = tanh(x@W + b); ait = exp(uit@u); ait /= (sum_s ait + EPS)
//   out[b,d] = sum_s x[b,s,d]*ait[b,s]
//
// R4 (polish): timed region = 2x 1.6GiB harness poison fills (~518us) + our
// kernels (~68us, already ~HBM roofline for the 419MB x read). Harvest the
// remaining non-x traffic + launch overhead:
//  - combine the 4 per-wave pool partials in LDS before the global store:
//    num shrinks [8192][4][200] -> [8192][200], saving ~39MB of HBM
//    write+read (~6us).
//  - fuse the final cross-chunk reduction into attn_kernel via a per-batch
//    atomic ticket (last of the 8 chunk-blocks reduces b). Removes the
//    reduce_kernel launch + drain (~8us), overlapping the reduction with the
//    attn tail. Counters are zeroed by prep each iteration (ws is poisoned).

typedef _Float16 half8 __attribute__((ext_vector_type(8)));
typedef _Float16 half4_ __attribute__((ext_vector_type(4)));
typedef float float4_ __attribute__((ext_vector_type(4)));

#define B_   1024
#define S_   512
#define D_   200
#define A_   100
#define NPAD 128
#define KPAD 224
#define SC   64          // s-rows per block
#define NCH  (S_ / SC)   // 8 chunks per batch
#define PITCH_H 232      // fp16 LDS pitch (232 halves = 464B; 2-way bank alias only)

#define WT_BYTES (NPAD * KPAD * 2)
#define UB_BYTES (NPAD * 2 * 4)
#define NUM_OFF  (WT_BYTES + UB_BYTES)                  // float num[8192][200]
#define NUM_BYTES ((size_t)B_ * NCH * D_ * 4)
#define DEN_OFF  (NUM_OFF + NUM_BYTES)                  // float den[8192]
#define DEN_BYTES ((size_t)B_ * NCH * 4)
#define CNT_OFF  (DEN_OFF + DEN_BYTES)                  // int cnt[1024]

// DPP row_shr add: after 1,2,4,8 steps, lane 15 of each 16-lane row holds the
// row sum (bound_ctrl=1 zero-fills shifted-in lanes).
#define DPP_ADD(v, ctrl)                                                     \
  v += __builtin_bit_cast(float, __builtin_amdgcn_update_dpp(                \
           0, __builtin_bit_cast(int, v), (ctrl), 0xF, 0xF, true))

__global__ void prep_kernel(const float* __restrict__ W,
                            const float* __restrict__ bias,
                            const float* __restrict__ u,
                            void* __restrict__ ws) {
  _Float16* wt = (_Float16*)ws;
  float* upad = (float*)((char*)ws + WT_BYTES);
  float* bpad = upad + NPAD;
  int* cnt = (int*)((char*)ws + CNT_OFF);
  int idx = blockIdx.x * 256 + threadIdx.x;
  if (idx < NPAD * KPAD) {
    int n = idx / KPAD;
    int k = idx % KPAD;
    float v = (n < A_ && k < D_) ? W[k * A_ + n] : 0.f;
    wt[idx] = (_Float16)v;
  }
  if (idx < B_) cnt[idx] = 0;   // ws is poisoned each iteration: must re-zero
  if (blockIdx.x == 0 && threadIdx.x < NPAD) {
    int t = threadIdx.x;
    upad[t] = (t < A_) ? u[t] : 0.f;
    bpad[t] = (t < A_) ? bias[t] : 0.f;
  }
}

__global__ __launch_bounds__(256, 4)
void attn_kernel(const float* __restrict__ x,
                 void* __restrict__ ws,
                 float* __restrict__ out) {
  __shared__ _Float16 xs[SC * PITCH_H];            // 29696 B
  __shared__ float score_part[4][SC];              // 1024 B
  __shared__ float e_lds[SC];                      // 256 B
  __shared__ __align__(16) float pool_part[4][D_]; // 3200 B
  __shared__ int last_flag;

  const int blk  = blockIdx.x;            // b*8 + chunk
  const int b    = blk >> 3;
  const int chunk= blk & 7;
  const int tid  = threadIdx.x;
  const int lane = tid & 63;
  const int wave = tid >> 6;
  const int lm   = lane & 15;
  const int lq   = lane >> 4;

  const _Float16* wt = (const _Float16*)ws;
  const float* upad = (const float*)((const char*)ws + WT_BYTES);
  const float* bpad = upad + NPAD;
  float* num_out = (float*)((char*)ws + NUM_OFF);
  float* den_out = (float*)((char*)ws + DEN_OFF);
  int* cnt = (int*)((char*)ws + CNT_OFF);

  // ---- Preload W B-fragments: wave w owns n-tiles {2w, 2w+1}.
  half8 Bfrag[2][7];
  float ureg[2], breg[2];
#pragma unroll
  for (int nn = 0; nn < 2; ++nn) {
    int a = (2 * wave + nn) * 16 + lm;
#pragma unroll
    for (int k = 0; k < 7; ++k)
      Bfrag[nn][k] = *(const half8*)(wt + (size_t)a * KPAD + k * 32 + lq * 8);
    ureg[nn] = upad[a];
    breg[nn] = bpad[a];
  }

  // ---- Stage x[b, chunk*64 : +64, :] -> LDS fp16, zero-pad cols 200..223.
  {
    int c  = tid & 63;     // float4 slot
    int r0 = tid >> 6;
    const float* xg = x + ((size_t)b * S_ + (size_t)chunk * SC) * D_;
#pragma unroll
    for (int j = 0; j < 16; ++j) {
      int row = r0 + 4 * j;
      if (c < 50) {
        float4_ v = *(const float4_*)(xg + row * D_ + c * 4);
        half4_ h = {(_Float16)v.x, (_Float16)v.y, (_Float16)v.z, (_Float16)v.w};
        *(half4_*)(&xs[row * PITCH_H + c * 4]) = h;
      } else if (c < 56) {
        half4_ z = {(_Float16)0.f, (_Float16)0.f, (_Float16)0.f, (_Float16)0.f};
        *(half4_*)(&xs[row * PITCH_H + c * 4]) = z;
      }
    }
  }
  __syncthreads();

  // ---- MFMA: uit-chunk = x_chunk @ W (64 x 128, K=224).
  float4_ acc[4][2];
#pragma unroll
  for (int m = 0; m < 4; ++m)
#pragma unroll
    for (int nn = 0; nn < 2; ++nn)
      acc[m][nn] = (float4_){0.f, 0.f, 0.f, 0.f};

#pragma unroll
  for (int k = 0; k < 7; ++k) {
#pragma unroll
    for (int m = 0; m < 4; ++m) {
      half8 af = *(const half8*)(&xs[(m * 16 + lm) * PITCH_H + k * 32 + lq * 8]);
#pragma unroll
      for (int nn = 0; nn < 2; ++nn)
        acc[m][nn] = __builtin_amdgcn_mfma_f32_16x16x32_f16(
            af, Bfrag[nn][k], acc[m][nn], 0, 0, 0);
    }
  }

  // ---- Epilogue: tanh(c + b[a]) * u[a]; DPP row-reduce over the 16 cols.
  // C/D layout: col(a)=lm, row(s_local)=m*16+lq*4+r. Lane lm==15 holds sums.
#pragma unroll
  for (int m = 0; m < 4; ++m) {
#pragma unroll
    for (int r = 0; r < 4; ++r) {
      float v = 0.f;
#pragma unroll
      for (int nn = 0; nn < 2; ++nn) {
        float z  = acc[m][nn][r] + breg[nn];
        float az = fabsf(z);
        float ez = __expf(az + az);
        float rc = __builtin_amdgcn_rcpf(ez + 1.f);
        float t  = fmaf(-2.f, rc, 1.f);
        t = copysignf(t, z);
        v = fmaf(t, ureg[nn], v);
      }
      DPP_ADD(v, 0x111);  // row_shr:1
      DPP_ADD(v, 0x112);  // row_shr:2
      DPP_ADD(v, 0x114);  // row_shr:4
      DPP_ADD(v, 0x118);  // row_shr:8 -> lane 15 of each row has the sum
      if (lm == 15) score_part[wave][m * 16 + lq * 4 + r] = v;
    }
  }
  __syncthreads();

  // ---- e_s = exp(score) (faithful: no max-subtract); block denominator.
  if (tid < SC) {
    float ssum = score_part[0][tid] + score_part[1][tid] +
                 score_part[2][tid] + score_part[3][tid];
    float e = __expf(ssum);
    e_lds[tid] = e;
    float d = e;
    d += __shfl_xor(d, 1);
    d += __shfl_xor(d, 2);
    d += __shfl_xor(d, 4);
    d += __shfl_xor(d, 8);
    d += __shfl_xor(d, 16);
    d += __shfl_xor(d, 32);
    if (tid == 0) den_out[blk] = d;
  }
  __syncthreads();

  // ---- Pool: wave w covers s in [16w, 16w+16); lanes 0..49 own 4 d-cols.
  if (lane < 50) {
    float4_ accv = {0.f, 0.f, 0.f, 0.f};
#pragma unroll
    for (int i = 0; i < 16; ++i) {
      int s = wave * 16 + i;
      float e = e_lds[s];
      half4_ h = *(const half4_*)(&xs[s * PITCH_H + lane * 4]);
      accv.x = fmaf(e, (float)h.x, accv.x);
      accv.y = fmaf(e, (float)h.y, accv.y);
      accv.z = fmaf(e, (float)h.z, accv.z);
      accv.w = fmaf(e, (float)h.w, accv.w);
    }
    *(float4_*)(&pool_part[wave][lane * 4]) = accv;
  }
  __syncthreads();

  // ---- Combine 4 wave partials in LDS; one 800B row to global per block.
  if (wave == 0 && lane < 50) {
    float4_ s0 = *(const float4_*)(&pool_part[0][lane * 4]);
    float4_ s1 = *(const float4_*)(&pool_part[1][lane * 4]);
    float4_ s2 = *(const float4_*)(&pool_part[2][lane * 4]);
    float4_ s3 = *(const float4_*)(&pool_part[3][lane * 4]);
    float4_ t = {s0.x + s1.x + s2.x + s3.x, s0.y + s1.y + s2.y + s3.y,
                 s0.z + s1.z + s2.z + s3.z, s0.w + s1.w + s2.w + s3.w};
    *(float4_*)(&num_out[(size_t)blk * D_ + lane * 4]) = t;
  }

  // ---- Split-K style ticket: last chunk-block of batch b does the divide.
  __threadfence();           // release our num/den stores (device scope)
  __syncthreads();
  if (tid == 0) {
    int old = atomicAdd(cnt + b, 1);
    last_flag = (old == NCH - 1);
  }
  __syncthreads();
  if (last_flag) {
    __threadfence();         // acquire the other 7 blocks' stores
    if (tid < D_) {
      float dsum = 0.f;
#pragma unroll
      for (int c = 0; c < NCH; ++c) dsum += den_out[b * NCH + c];
      float s = 0.f;
#pragma unroll
      for (int c = 0; c < NCH; ++c)
        s += num_out[((size_t)b * NCH + c) * D_ + tid];
      out[(size_t)b * D_ + tid] = s / (dsum + 1e-7f);
    }
  }
}

extern "C" void kernel_launch(void* const* d_in, const int* in_sizes, int n_in,
                              void* d_out, int out_size, void* d_ws, size_t ws_size,
                              hipStream_t stream) {
  const float* x = (const float*)d_in[0];
  const float* W = (const float*)d_in[1];
  const float* b = (const float*)d_in[2];
  const float* u = (const float*)d_in[3];
  float* out = (float*)d_out;

  int prep_elems = NPAD * KPAD;
  int prep_blocks = (prep_elems + 255) / 256;
  prep_kernel<<<prep_blocks, 256, 0, stream>>>(W, b, u, d_ws);
  attn_kernel<<<B_ * NCH, 256, 0, stream>>>(x, d_ws, out);
}

// Round 2
// 582.814 us; speedup vs baseline: 4.5091x; 4.5091x over previous
//
#include <hip/hip_runtime.h>
#include <math.h>

// Problem: B=1024, S=512, D=200, A=100
//   uit = tanh(x@W + b); ait = exp(uit@u); ait /= (sum_s ait + EPS)
//   out[b,d] = sum_s x[b,s,d]*ait[b,s]
//
// R5: revert R4's fused split-K ticket. __threadfence() (agent-scope fence)
// on gfx950 compiles to whole-L2 writeback/invalidate (per-XCD L2s are not
// cross-coherent); executing it in all 8192 blocks serialized the dispatch
// (2388us, 1.2% HBM). Back to the R3 two-kernel structure (no cross-block
// communication), KEEPING the one sound R4 change: the 4 per-wave pool
// partials are combined in LDS before the global store, so num shrinks
// [8192][4][200] -> [8192][200] (saves ~39MB of HBM write+read vs R3).

typedef _Float16 half8 __attribute__((ext_vector_type(8)));
typedef _Float16 half4_ __attribute__((ext_vector_type(4)));
typedef float float4_ __attribute__((ext_vector_type(4)));

#define B_   1024
#define S_   512
#define D_   200
#define A_   100
#define NPAD 128
#define KPAD 224
#define SC   64          // s-rows per block
#define NCH  (S_ / SC)   // 8 chunks per batch
#define PITCH_H 232      // fp16 LDS pitch (232 halves = 464B; 2-way bank alias only)

#define WT_BYTES (NPAD * KPAD * 2)
#define UB_BYTES (NPAD * 2 * 4)
#define NUM_OFF  (WT_BYTES + UB_BYTES)                  // float num[8192][200]
#define NUM_BYTES ((size_t)B_ * NCH * D_ * 4)
#define DEN_OFF  (NUM_OFF + NUM_BYTES)                  // float den[8192]

// DPP row_shr add: after 1,2,4,8 steps, lane 15 of each 16-lane row holds the
// row sum (bound_ctrl=1 zero-fills shifted-in lanes).
#define DPP_ADD(v, ctrl)                                                     \
  v += __builtin_bit_cast(float, __builtin_amdgcn_update_dpp(                \
           0, __builtin_bit_cast(int, v), (ctrl), 0xF, 0xF, true))

__global__ void prep_kernel(const float* __restrict__ W,
                            const float* __restrict__ bias,
                            const float* __restrict__ u,
                            void* __restrict__ ws) {
  _Float16* wt = (_Float16*)ws;
  float* upad = (float*)((char*)ws + WT_BYTES);
  float* bpad = upad + NPAD;
  int idx = blockIdx.x * 256 + threadIdx.x;
  if (idx < NPAD * KPAD) {
    int n = idx / KPAD;
    int k = idx % KPAD;
    float v = (n < A_ && k < D_) ? W[k * A_ + n] : 0.f;
    wt[idx] = (_Float16)v;
  }
  if (blockIdx.x == 0 && threadIdx.x < NPAD) {
    int t = threadIdx.x;
    upad[t] = (t < A_) ? u[t] : 0.f;
    bpad[t] = (t < A_) ? bias[t] : 0.f;
  }
}

__global__ __launch_bounds__(256, 4)
void attn_kernel(const float* __restrict__ x,
                 void* __restrict__ ws) {
  __shared__ _Float16 xs[SC * PITCH_H];            // 29696 B
  __shared__ float score_part[4][SC];              // 1024 B
  __shared__ float e_lds[SC];                      // 256 B
  __shared__ __align__(16) float pool_part[4][D_]; // 3200 B

  const int blk  = blockIdx.x;            // b*8 + chunk
  const int b    = blk >> 3;
  const int chunk= blk & 7;
  const int tid  = threadIdx.x;
  const int lane = tid & 63;
  const int wave = tid >> 6;
  const int lm   = lane & 15;
  const int lq   = lane >> 4;

  const _Float16* wt = (const _Float16*)ws;
  const float* upad = (const float*)((const char*)ws + WT_BYTES);
  const float* bpad = upad + NPAD;
  float* num_out = (float*)((char*)ws + NUM_OFF);
  float* den_out = (float*)((char*)ws + DEN_OFF);

  // ---- Preload W B-fragments: wave w owns n-tiles {2w, 2w+1}.
  half8 Bfrag[2][7];
  float ureg[2], breg[2];
#pragma unroll
  for (int nn = 0; nn < 2; ++nn) {
    int a = (2 * wave + nn) * 16 + lm;
#pragma unroll
    for (int k = 0; k < 7; ++k)
      Bfrag[nn][k] = *(const half8*)(wt + (size_t)a * KPAD + k * 32 + lq * 8);
    ureg[nn] = upad[a];
    breg[nn] = bpad[a];
  }

  // ---- Stage x[b, chunk*64 : +64, :] -> LDS fp16, zero-pad cols 200..223.
  {
    int c  = tid & 63;     // float4 slot
    int r0 = tid >> 6;
    const float* xg = x + ((size_t)b * S_ + (size_t)chunk * SC) * D_;
#pragma unroll
    for (int j = 0; j < 16; ++j) {
      int row = r0 + 4 * j;
      if (c < 50) {
        float4_ v = *(const float4_*)(xg + row * D_ + c * 4);
        half4_ h = {(_Float16)v.x, (_Float16)v.y, (_Float16)v.z, (_Float16)v.w};
        *(half4_*)(&xs[row * PITCH_H + c * 4]) = h;
      } else if (c < 56) {
        half4_ z = {(_Float16)0.f, (_Float16)0.f, (_Float16)0.f, (_Float16)0.f};
        *(half4_*)(&xs[row * PITCH_H + c * 4]) = z;
      }
    }
  }
  __syncthreads();

  // ---- MFMA: uit-chunk = x_chunk @ W (64 x 128, K=224).
  float4_ acc[4][2];
#pragma unroll
  for (int m = 0; m < 4; ++m)
#pragma unroll
    for (int nn = 0; nn < 2; ++nn)
      acc[m][nn] = (float4_){0.f, 0.f, 0.f, 0.f};

#pragma unroll
  for (int k = 0; k < 7; ++k) {
#pragma unroll
    for (int m = 0; m < 4; ++m) {
      half8 af = *(const half8*)(&xs[(m * 16 + lm) * PITCH_H + k * 32 + lq * 8]);
#pragma unroll
      for (int nn = 0; nn < 2; ++nn)
        acc[m][nn] = __builtin_amdgcn_mfma_f32_16x16x32_f16(
            af, Bfrag[nn][k], acc[m][nn], 0, 0, 0);
    }
  }

  // ---- Epilogue: tanh(c + b[a]) * u[a]; DPP row-reduce over the 16 cols.
  // C/D layout: col(a)=lm, row(s_local)=m*16+lq*4+r. Lane lm==15 holds sums.
#pragma unroll
  for (int m = 0; m < 4; ++m) {
#pragma unroll
    for (int r = 0; r < 4; ++r) {
      float v = 0.f;
#pragma unroll
      for (int nn = 0; nn < 2; ++nn) {
        float z  = acc[m][nn][r] + breg[nn];
        float az = fabsf(z);
        float ez = __expf(az + az);
        float rc = __builtin_amdgcn_rcpf(ez + 1.f);
        float t  = fmaf(-2.f, rc, 1.f);
        t = copysignf(t, z);
        v = fmaf(t, ureg[nn], v);
      }
      DPP_ADD(v, 0x111);  // row_shr:1
      DPP_ADD(v, 0x112);  // row_shr:2
      DPP_ADD(v, 0x114);  // row_shr:4
      DPP_ADD(v, 0x118);  // row_shr:8 -> lane 15 of each row has the sum
      if (lm == 15) score_part[wave][m * 16 + lq * 4 + r] = v;
    }
  }
  __syncthreads();

  // ---- e_s = exp(score) (faithful: no max-subtract); block denominator.
  if (tid < SC) {
    float ssum = score_part[0][tid] + score_part[1][tid] +
                 score_part[2][tid] + score_part[3][tid];
    float e = __expf(ssum);
    e_lds[tid] = e;
    float d = e;
    d += __shfl_xor(d, 1);
    d += __shfl_xor(d, 2);
    d += __shfl_xor(d, 4);
    d += __shfl_xor(d, 8);
    d += __shfl_xor(d, 16);
    d += __shfl_xor(d, 32);
    if (tid == 0) den_out[blk] = d;
  }
  __syncthreads();

  // ---- Pool: wave w covers s in [16w, 16w+16); lanes 0..49 own 4 d-cols.
  if (lane < 50) {
    float4_ accv = {0.f, 0.f, 0.f, 0.f};
#pragma unroll
    for (int i = 0; i < 16; ++i) {
      int s = wave * 16 + i;
      float e = e_lds[s];
      half4_ h = *(const half4_*)(&xs[s * PITCH_H + lane * 4]);
      accv.x = fmaf(e, (float)h.x, accv.x);
      accv.y = fmaf(e, (float)h.y, accv.y);
      accv.z = fmaf(e, (float)h.z, accv.z);
      accv.w = fmaf(e, (float)h.w, accv.w);
    }
    *(float4_*)(&pool_part[wave][lane * 4]) = accv;
  }
  __syncthreads();

  // ---- Combine 4 wave partials in LDS; one 800B row to global per block.
  if (wave == 0 && lane < 50) {
    float4_ s0 = *(const float4_*)(&pool_part[0][lane * 4]);
    float4_ s1 = *(const float4_*)(&pool_part[1][lane * 4]);
    float4_ s2 = *(const float4_*)(&pool_part[2][lane * 4]);
    float4_ s3 = *(const float4_*)(&pool_part[3][lane * 4]);
    float4_ t = {s0.x + s1.x + s2.x + s3.x, s0.y + s1.y + s2.y + s3.y,
                 s0.z + s1.z + s2.z + s3.z, s0.w + s1.w + s2.w + s3.w};
    *(float4_*)(&num_out[(size_t)blk * D_ + lane * 4]) = t;
  }
}

__global__ __launch_bounds__(256)
void reduce_kernel(const void* __restrict__ ws, float* __restrict__ out) {
  const float* num = (const float*)((const char*)ws + NUM_OFF);
  const float* den = (const float*)((const char*)ws + DEN_OFF);
  int b = blockIdx.x;
  int tid = threadIdx.x;
  if (tid < D_) {
    float d = 0.f;
#pragma unroll
    for (int c = 0; c < NCH; ++c) d += den[b * NCH + c];
    float s = 0.f;
#pragma unroll
    for (int c = 0; c < NCH; ++c)
      s += num[((size_t)b * NCH + c) * D_ + tid];
    out[(size_t)b * D_ + tid] = s / (d + 1e-7f);
  }
}

extern "C" void kernel_launch(void* const* d_in, const int* in_sizes, int n_in,
                              void* d_out, int out_size, void* d_ws, size_t ws_size,
                              hipStream_t stream) {
  const float* x = (const float*)d_in[0];
  const float* W = (const float*)d_in[1];
  const float* b = (const float*)d_in[2];
  const float* u = (const float*)d_in[3];
  float* out = (float*)d_out;

  int prep_elems = NPAD * KPAD;
  int prep_blocks = (prep_elems + 255) / 256;
  prep_kernel<<<prep_blocks, 256, 0, stream>>>(W, b, u, d_ws);
  attn_kernel<<<B_ * NCH, 256, 0, stream>>>(x, d_ws);
  reduce_kernel<<<B_, 256, 0, stream>>>(d_ws, out);
}